// Round 1
// baseline (1108.715 us; speedup 1.0000x reference)
//
#include <hip/hip_runtime.h>

#define N_NODES 50000
#define N_EDGES 640000
#define DIM 128

// ---------------------------------------------------------------------------
// Kernel 1: per-node projections.
//   P[n][0:128]   = NF[n] @ W[0:128, :]    (W1, for row gather)
//   P[n][128:256] = NF[n] @ W[128:256, :]  (W2, for col gather)
// 256 threads/block; thread t owns output column t of [P1|P2] and keeps the
// matching W column (128 f32) in registers. Node rows staged 8 at a time in
// LDS and read back as broadcast float4 (no bank conflicts).
// ---------------------------------------------------------------------------
__global__ __launch_bounds__(256) void node_precompute(
    const float* __restrict__ NF,
    const float* __restrict__ W,
    float* __restrict__ P)
{
    const int tid = threadIdx.x;          // 0..255
    const int col = tid & 127;            // column within W1/W2
    const int rowoff = (tid >> 7) * 128;  // 0 -> W1, 128 -> W2

    float wcol[128];
#pragma unroll
    for (int k = 0; k < 128; ++k)
        wcol[k] = W[(size_t)(k + rowoff) * 128 + col];

    __shared__ __align__(16) float snf[8][128];

    const int ntiles = N_NODES / 8;  // 6250, exact
    const int b0 = (int)(((long long)ntiles * blockIdx.x) / gridDim.x);
    const int b1 = (int)(((long long)ntiles * (blockIdx.x + 1)) / gridDim.x);

    for (int t = b0; t < b1; ++t) {
        const int n0 = t * 8;
        // 8 rows * 128 f32 = 1024 floats = 256 float4 -> 1 per thread, coalesced
        const float4* src = (const float4*)(NF + (size_t)n0 * 128);
        ((float4*)snf)[tid] = src[tid];
        __syncthreads();

        float acc[8];
#pragma unroll
        for (int e = 0; e < 8; ++e) acc[e] = 0.0f;

#pragma unroll
        for (int k = 0; k < 128; k += 4) {
            const float w0 = wcol[k + 0];
            const float w1 = wcol[k + 1];
            const float w2 = wcol[k + 2];
            const float w3 = wcol[k + 3];
#pragma unroll
            for (int e = 0; e < 8; ++e) {
                const float4 v = *(const float4*)&snf[e][k];  // broadcast read
                float a = acc[e];
                a = fmaf(v.x, w0, a);
                a = fmaf(v.y, w1, a);
                a = fmaf(v.z, w2, a);
                a = fmaf(v.w, w3, a);
                acc[e] = a;
            }
        }
        __syncthreads();  // LDS reuse guard

#pragma unroll
        for (int e = 0; e < 8; ++e)
            P[(size_t)(n0 + e) * 256 + tid] = acc[e];  // coalesced 1 KiB/row-pair
    }
}

// ---------------------------------------------------------------------------
// Kernel 2: fused edge gate.
//   out[e][j] = ef[e][j] * sigmoid(P[row_e][j] + P[col_e][128+j] + b[j]
//                                  + sum_k ef[e][k] * W3[k][j])
// 128 threads/block; thread j owns W3 column j (128 f32 in registers) + b[j].
// Per 8-edge tile: stage EF in LDS, issue the 16 random P-gathers EARLY
// (needed only in the epilogue -> latency hidden under the 1024-FMA block).
// ---------------------------------------------------------------------------
__global__ __launch_bounds__(128) void edge_gate(
    const float* __restrict__ EF,
    const int* __restrict__ EIDX,   // [2][N_EDGES]
    const float* __restrict__ P,    // [N_NODES][256]
    const float* __restrict__ W,
    const float* __restrict__ B,
    float* __restrict__ OUT)
{
    const int j = threadIdx.x;  // 0..127

    float wcol[128];
#pragma unroll
    for (int k = 0; k < 128; ++k)
        wcol[k] = W[(size_t)(256 + k) * 128 + j];  // W3 column j
    const float bias = B[j];

    __shared__ __align__(16) float sef[8][128];
    __shared__ int sidx[16];  // rows[0:8], cols[8:16]

    const int ntiles = N_EDGES / 8;  // 80000, exact
    const int b0 = (int)(((long long)ntiles * blockIdx.x) / gridDim.x);
    const int b1 = (int)(((long long)ntiles * (blockIdx.x + 1)) / gridDim.x);

    for (int t = b0; t < b1; ++t) {
        const int e0 = t * 8;

        // stage EF tile: 1024 floats / 128 threads = 2 float4 each, coalesced
        const float4* src = (const float4*)(EF + (size_t)e0 * 128);
        ((float4*)sef)[j] = src[j];
        ((float4*)sef)[j + 128] = src[j + 128];
        if (j < 8)       sidx[j] = EIDX[e0 + j];
        else if (j < 16) sidx[j] = EIDX[N_EDGES + e0 + (j - 8)];
        __syncthreads();

        // issue all 16 gathers early; each is a coalesced 512B segment
        float p1[8], p2[8];
#pragma unroll
        for (int e = 0; e < 8; ++e) {
            p1[e] = P[(size_t)sidx[e]     * 256 + j];
            p2[e] = P[(size_t)sidx[8 + e] * 256 + 128 + j];
        }

        float acc[8];
#pragma unroll
        for (int e = 0; e < 8; ++e) acc[e] = 0.0f;

#pragma unroll
        for (int k = 0; k < 128; k += 4) {
            const float w0 = wcol[k + 0];
            const float w1 = wcol[k + 1];
            const float w2 = wcol[k + 2];
            const float w3 = wcol[k + 3];
#pragma unroll
            for (int e = 0; e < 8; ++e) {
                const float4 v = *(const float4*)&sef[e][k];  // broadcast read
                float a = acc[e];
                a = fmaf(v.x, w0, a);
                a = fmaf(v.y, w1, a);
                a = fmaf(v.z, w2, a);
                a = fmaf(v.w, w3, a);
                acc[e] = a;
            }
        }

        // read own ef element before LDS reuse
        float efj[8];
#pragma unroll
        for (int e = 0; e < 8; ++e) efj[e] = sef[e][j];

#pragma unroll
        for (int e = 0; e < 8; ++e) {
            const float pre  = acc[e] + p1[e] + p2[e] + bias;
            const float gate = 1.0f / (1.0f + __expf(-pre));
            OUT[(size_t)(e0 + e) * 128 + j] = efj[e] * gate;  // coalesced
        }
        __syncthreads();  // LDS reuse guard
    }
}

// ---------------------------------------------------------------------------
extern "C" void kernel_launch(void* const* d_in, const int* in_sizes, int n_in,
                              void* d_out, int out_size, void* d_ws, size_t ws_size,
                              hipStream_t stream)
{
    const float* NF   = (const float*)d_in[0];  // [50000,128] f32
    const int*   EIDX = (const int*)d_in[1];    // [2,640000] int32
    const float* EF   = (const float*)d_in[2];  // [640000,128] f32
    const float* W    = (const float*)d_in[3];  // [384,128] f32
    const float* B    = (const float*)d_in[4];  // [128] f32
    float*       OUT  = (float*)d_out;          // [640000,128] f32

    float* P = (float*)d_ws;  // [50000][256] f32 = 51.2 MB scratch

    node_precompute<<<1024, 256, 0, stream>>>(NF, W, P);
    edge_gate<<<2048, 128, 0, stream>>>(EF, EIDX, P, W, B, OUT);
}